// Round 3
// baseline (153.477 us; speedup 1.0000x reference)
//
#include <hip/hip_runtime.h>

// Problem constants (from reference)
#define DIM     1024
#define N_CLS   10
#define NROWS   16384
#define IMG     784

// Only columns [0, 784) of ref are nonzero (zero-padded reference) -> only
// those z columns matter. Pad the working width to 832 cols = 208 float4 so
// 16 sublanes x 13 steps tile it exactly; LDS ref is zero-padded in the tail,
// so the math stays EXACT while we skip 18.6% of z traffic.
#define NF4      196   // float4 per row actually used (784/4)
#define NF4_PAD  208   // 13 * 16
#define NSTEP    13
#define LSTRIDE  208   // float4 stride per class in LDS (33280 B total)

#define ROWS_PER_BLK 16  // 4 waves x 4 rows (one row per 16-lane group)

// Rolling prefetch depth (pairs of re/im loads). 6 pairs = 12 KB in flight
// per wave (vs 2 KB at depth-1) -> ~190 KB/CU outstanding at 16 waves/CU,
// far above the ~9 KB/CU Little's-law requirement for 6.3 TB/s.
#define PF_DEPTH 6

typedef float f32x4 __attribute__((ext_vector_type(4)));
typedef float f32x2 __attribute__((ext_vector_type(2)));

static __device__ __forceinline__ f32x2 lo2(f32x4 v) {
  return __builtin_shufflevector(v, v, 0, 1);
}
static __device__ __forceinline__ f32x2 hi2(f32x4 v) {
  return __builtin_shufflevector(v, v, 2, 3);
}

// Packed dual-FP32 FMA (the 157 TF path). Compiler never forms this from
// scalar code; non-volatile asm so the scheduler can still move it.
static __device__ __forceinline__ void pk_fma(f32x2& acc, f32x2 a, f32x2 b) {
  asm("v_pk_fma_f32 %0, %1, %2, %0" : "+v"(acc) : "v"(a), "v"(b));
}

// ---------------------------------------------------------------------------
// Wave64 sum via DPP; result valid in lane 63 (per-block canon normalization).
// ---------------------------------------------------------------------------
__device__ __forceinline__ float wave64_sum(float x) {
#define DPP_ADD(ctrl, rmask, bmask)                                           \
  x += __int_as_float(__builtin_amdgcn_update_dpp(                            \
      0, __float_as_int(x), ctrl, rmask, bmask, true));
  DPP_ADD(0x111, 0xf, 0xf)  // row_shr:1
  DPP_ADD(0x112, 0xf, 0xf)  // row_shr:2
  DPP_ADD(0x114, 0xf, 0xe)  // row_shr:4
  DPP_ADD(0x118, 0xf, 0xc)  // row_shr:8
  DPP_ADD(0x142, 0xa, 0xf)  // row_bcast:15
  DPP_ADD(0x143, 0xc, 0xf)  // row_bcast:31
#undef DPP_ADD
  return x;  // total in lane 63
}

// Sum within each 16-lane DPP row; result valid in lane 15 of each row.
__device__ __forceinline__ float group16_sum(float x) {
#define DPP_ADD(ctrl)                                                         \
  x += __int_as_float(__builtin_amdgcn_update_dpp(                            \
      0, __float_as_int(x), ctrl, 0xf, 0xf, true));
  DPP_ADD(0x111)  // row_shr:1
  DPP_ADD(0x112)  // row_shr:2
  DPP_ADD(0x114)  // row_shr:4
  DPP_ADD(0x118)  // row_shr:8
#undef DPP_ADD
  return x;
}

// ---------------------------------------------------------------------------
// Single fused kernel: stage canon -> LDS (padded, zero tail), normalize it
// in LDS, then swap-test 16 rows per block. Lane (g,s): group g owns row
// row0+g, sublane s owns float4 column s+16j. All z loads and ds_reads are
// one base vaddr + imm offsets. Main loop uses a depth-6 rolling register
// prefetch so each wave keeps 12 x 1 KiB loads in flight (counted vmcnt).
// ---------------------------------------------------------------------------
__global__ __launch_bounds__(256, 4) void swaptest_kernel(
    const float* __restrict__ zre, const float* __restrict__ zim,
    const float* __restrict__ canon, float* __restrict__ out) {
  __shared__ f32x4 lref[N_CLS * LSTRIDE];  // 33280 B -> 4 blocks/CU

  const int t = threadIdx.x;
  const int lane = t & 63;
  const int wave = t >> 6;

  // ---- stage canon (zero-padding cols >= 784) ----
#pragma unroll
  for (int c = 0; c < N_CLS; ++c) {
    if (t < NF4_PAD) {
      f32x4 v = {0.f, 0.f, 0.f, 0.f};
      if (t < NF4) v = ((const f32x4*)canon)[c * NF4 + t];
      lref[c * LSTRIDE + t] = v;
    }
  }
  __syncthreads();

  // ---- normalize each class in LDS (wave w handles classes w, w+4, w+8) ----
  for (int c = wave; c < N_CLS; c += 4) {
    float ss = 0.f;
    for (int i = lane; i < NF4_PAD; i += 64) {
      f32x4 v = lref[c * LSTRIDE + i];
      ss += v.x * v.x + v.y * v.y + v.z * v.z + v.w * v.w;
    }
    ss = wave64_sum(ss);                       // lane 63
    float inv = __shfl(1.0f / sqrtf(ss), 63);  // broadcast
    for (int i = lane; i < NF4_PAD; i += 64) {
      f32x4 v = lref[c * LSTRIDE + i];
      v.x *= inv; v.y *= inv; v.z *= inv; v.w *= inv;
      lref[c * LSTRIDE + i] = v;
    }
  }
  __syncthreads();

  // ---- swap test ----
  const int s = lane & 15;
  const int g = lane >> 4;
  const int row = blockIdx.x * ROWS_PER_BLK + wave * 4 + g;

  const f32x4* pr = (const f32x4*)(zre + ((size_t)row << 10)) + s;
  const f32x4* pi = (const f32x4*)(zim + ((size_t)row << 10)) + s;

  f32x2 accr[N_CLS], acci[N_CLS];
#pragma unroll
  for (int c = 0; c < N_CLS; ++c) {
    accr[c] = (f32x2){0.f, 0.f};
    acci[c] = (f32x2){0.f, 0.f};
  }

  // Rolling prefetch ring. All indices are compile-time after unrolling
  // (rule: runtime-indexed ext_vector arrays go to scratch).
  f32x4 bzr[PF_DEPTH], bzi[PF_DEPTH];
#pragma unroll
  for (int j = 0; j < PF_DEPTH; ++j) {
    bzr[j] = pr[j * 16];  // byte offset j*256, imm-foldable
    bzi[j] = pi[j * 16];
  }

#pragma unroll
  for (int j = 0; j < NSTEP; ++j) {
    const int b = j % PF_DEPTH;
    const f32x4 zr = bzr[b];
    const f32x4 zi = bzi[b];
    if (j + PF_DEPTH < NSTEP) {
      bzr[b] = pr[(j + PF_DEPTH) * 16];
      bzi[b] = pi[(j + PF_DEPTH) * 16];
    }
#pragma unroll
    for (int c = 0; c < N_CLS; ++c) {
      // 4-way broadcast across groups (same address) -> conflict-free.
      const f32x4 rv = lref[c * LSTRIDE + j * 16 + s];
      pk_fma(accr[c], lo2(zr), lo2(rv));
      pk_fma(accr[c], hi2(zr), hi2(rv));
      pk_fma(acci[c], lo2(zi), lo2(rv));
      pk_fma(acci[c], hi2(zi), hi2(rv));
    }
  }

  // 16-lane reductions; totals land in lane 15 of each group.
#pragma unroll
  for (int c = 0; c < N_CLS; ++c) {
    float sr = group16_sum(accr[c].x + accr[c].y);
    float si = group16_sum(acci[c].x + acci[c].y);
    if (s == 15) {
      out[(size_t)row * N_CLS + c] = sr * sr + si * si;
    }
  }
}

// ---------------------------------------------------------------------------
extern "C" void kernel_launch(void* const* d_in, const int* in_sizes, int n_in,
                              void* d_out, int out_size, void* d_ws,
                              size_t ws_size, hipStream_t stream) {
  const float* z_re = (const float*)d_in[0];
  const float* z_im = (const float*)d_in[1];
  const float* canon = (const float*)d_in[2];
  float* out = (float*)d_out;
  (void)d_ws; (void)ws_size;

  const int nblk = NROWS / ROWS_PER_BLK;  // 1024 blocks = 4/CU, one clean round
  swaptest_kernel<<<nblk, 256, 0, stream>>>(z_re, z_im, canon, out);
}